// Round 2
// baseline (214.024 us; speedup 1.0000x reference)
//
#include <hip/hip_runtime.h>

// QCausalConv1D: int8 depthwise causal conv1d (K=4) + bias + SiLU + requant.
// B=8, D=4096, L=4096. Inputs widened to int32; OUTPUT is also read as int32
// by the harness (integer reference dtype -> np.int32 readback).
//
// Memory-bound: 512 MiB x-read + 512 MiB out-write => ~165us floor @ 6.3 TB/s.

#define Dq 4096
#define Lq 4096
#define VPR (Lq / 4)   // int4 vectors per row = 1024

__global__ void __launch_bounds__(256)
qconv1d_kernel(const int* __restrict__ x,       // (B, D, L) int32 in [-128,127]
               const int* __restrict__ w,       // (D, K=4)
               const int* __restrict__ bias,    // (D,)
               const float* __restrict__ s_in,
               const float* __restrict__ s_w,
               const float* __restrict__ s_out,
               const float* __restrict__ s_b,
               int* __restrict__ out,           // (B, D, L) int32
               int nvec) {
    const float sc      = s_in[0] * s_w[0];     // dequant scale for conv sum
    const float inv_out = 1.0f / s_out[0];
    const float sb      = s_b[0];

    const int4* __restrict__ xv = (const int4*)x;
    const int4* __restrict__ wv = (const int4*)w;
    int4* __restrict__ ov = (int4*)out;

    int idx    = blockIdx.x * blockDim.x + threadIdx.x;
    int stride = gridDim.x * blockDim.x;

    for (; idx < nvec; idx += stride) {
        const int v   = idx & (VPR - 1);        // vector index within row
        const int row = idx >> 10;              // b*D + d
        const int d   = row & (Dq - 1);

        int4 cur = xv[idx];
        int4 prev;
        if (v == 0) {
            prev = make_int4(0, 0, 0, 0);       // causal left padding
        } else {
            prev = xv[idx - 1];                 // neighbor vector: L1/L2 hit
        }
        const int4 wt = wv[d];                  // taps w[d][0..3] (L2-resident)
        const float bf = (float)bias[d] * sb;

        // xs[j] = x[l0 - 4 + j], l0 = 4*v
        int xs[8] = {prev.x, prev.y, prev.z, prev.w, cur.x, cur.y, cur.z, cur.w};

        int4 o;
        int* op = &o.x;
        #pragma unroll
        for (int j = 0; j < 4; ++j) {
            // y[l] = x[l-3]*w0 + x[l-2]*w1 + x[l-1]*w2 + x[l]*w3
            int s = xs[j + 1] * wt.x + xs[j + 2] * wt.y
                  + xs[j + 3] * wt.z + xs[j + 4] * wt.w;
            float y = (float)s * sc + bf;
            float sig = 1.0f / (1.0f + __expf(-y));
            float sil = y * sig;
            float q = rintf(sil * inv_out);      // round-half-even = jnp.round
            q = fminf(fmaxf(q, -128.0f), 127.0f);
            op[j] = (int)q;
        }
        ov[idx] = o;
    }
}

extern "C" void kernel_launch(void* const* d_in, const int* in_sizes, int n_in,
                              void* d_out, int out_size, void* d_ws, size_t ws_size,
                              hipStream_t stream) {
    const int*   x    = (const int*)d_in[0];
    const int*   w    = (const int*)d_in[1];
    const int*   bias = (const int*)d_in[2];
    const float* s_in = (const float*)d_in[3];
    const float* s_w  = (const float*)d_in[4];
    const float* s_out= (const float*)d_in[5];
    const float* s_b  = (const float*)d_in[6];
    int* out = (int*)d_out;

    const int nvec = out_size / 4;              // B*D*L/4 int4 vectors
    const int block = 256;
    int grid = 8192;                            // grid-stride, ~16 vec/thread
    if (grid > (nvec + block - 1) / block) grid = (nvec + block - 1) / block;

    qconv1d_kernel<<<grid, block, 0, stream>>>(x, w, bias, s_in, s_w, s_out, s_b,
                                               out, nvec);
}

// Round 3
// 180.766 us; speedup vs baseline: 1.1840x; 1.1840x over previous
//
#include <hip/hip_runtime.h>

// QCausalConv1D: int8 depthwise causal conv1d (K=4) + bias + SiLU + requant.
// B=8, D=4096, L=4096. Inputs widened to int32; output read back as int32.
//
// Memory-bound: 512 MiB x-read + 512 MiB out-write => ~163us floor @ 6.6 TB/s
// (fillBuffer's measured write BW). Round 2 grid-stride version: 214us / 5.0 TB/s.
// This version: one block per (b,d) row, fully unrolled 4 vec/thread, all loads
// issued up front (MLP), nontemporal stores (output never re-read).

#define Dq 4096
#define VPR 1024          // int4 vectors per row (L=4096 / 4)

typedef int int4v __attribute__((ext_vector_type(4)));

__global__ void __launch_bounds__(256)
qconv1d_kernel(const int* __restrict__ x,       // (B, D, L) int32 in [-128,127]
               const int* __restrict__ w,       // (D, K=4)
               const int* __restrict__ bias,    // (D,)
               const float* __restrict__ s_in,
               const float* __restrict__ s_w,
               const float* __restrict__ s_out,
               const float* __restrict__ s_b,
               int* __restrict__ out) {
    const int row  = blockIdx.x;                // b*D + d
    const int d    = row & (Dq - 1);
    const int t    = threadIdx.x;
    const long base = (long)row * VPR;

    const int4v* __restrict__ xv = (const int4v*)x;
    const int4v* __restrict__ wv = (const int4v*)w;
    int4v* __restrict__ ov = (int4v*)out;

    // Issue all 8 row loads up front for maximum memory-level parallelism.
    int4v cur0 = xv[base + 0 * 256 + t];
    int4v cur1 = xv[base + 1 * 256 + t];
    int4v cur2 = xv[base + 2 * 256 + t];
    int4v cur3 = xv[base + 3 * 256 + t];
    int4v zero = {0, 0, 0, 0};
    int4v prev0 = (t == 0) ? zero : xv[base + 0 * 256 + t - 1];
    int4v prev1 = xv[base + 1 * 256 + t - 1];
    int4v prev2 = xv[base + 2 * 256 + t - 1];
    int4v prev3 = xv[base + 3 * 256 + t - 1];

    const int4v wt = wv[d];                     // taps w[d][0..3] (L2-resident)
    const float sc      = s_in[0] * s_w[0];
    const float inv_out = 1.0f / s_out[0];
    const float bf      = (float)bias[d] * s_b[0];

    int4v o0, o1, o2, o3;
    #pragma unroll
    for (int g = 0; g < 4; ++g) {
        int4v cur  = (g == 0) ? cur0  : (g == 1) ? cur1  : (g == 2) ? cur2  : cur3;
        int4v prev = (g == 0) ? prev0 : (g == 1) ? prev1 : (g == 2) ? prev2 : prev3;
        int xs[8] = {prev[0], prev[1], prev[2], prev[3],
                     cur[0],  cur[1],  cur[2],  cur[3]};
        int4v o;
        #pragma unroll
        for (int j = 0; j < 4; ++j) {
            // y[l] = x[l-3]*w0 + x[l-2]*w1 + x[l-1]*w2 + x[l]*w3
            int s = xs[j + 1] * wt[0] + xs[j + 2] * wt[1]
                  + xs[j + 3] * wt[2] + xs[j + 4] * wt[3];
            float y = (float)s * sc + bf;
            float sig = 1.0f / (1.0f + __expf(-y));
            float sil = y * sig;
            float q = rintf(sil * inv_out);      // round-half-even = jnp.round
            q = fminf(fmaxf(q, -128.0f), 127.0f);
            o[j] = (int)q;
        }
        if (g == 0) o0 = o; else if (g == 1) o1 = o; else if (g == 2) o2 = o; else o3 = o;
    }

    __builtin_nontemporal_store(o0, &ov[base + 0 * 256 + t]);
    __builtin_nontemporal_store(o1, &ov[base + 1 * 256 + t]);
    __builtin_nontemporal_store(o2, &ov[base + 2 * 256 + t]);
    __builtin_nontemporal_store(o3, &ov[base + 3 * 256 + t]);
}

extern "C" void kernel_launch(void* const* d_in, const int* in_sizes, int n_in,
                              void* d_out, int out_size, void* d_ws, size_t ws_size,
                              hipStream_t stream) {
    const int*   x    = (const int*)d_in[0];
    const int*   w    = (const int*)d_in[1];
    const int*   bias = (const int*)d_in[2];
    const float* s_in = (const float*)d_in[3];
    const float* s_w  = (const float*)d_in[4];
    const float* s_out= (const float*)d_in[5];
    const float* s_b  = (const float*)d_in[6];
    int* out = (int*)d_out;

    const int rows = out_size / (VPR * 4);      // B*D = 32768
    qconv1d_kernel<<<rows, 256, 0, stream>>>(x, w, bias, s_in, s_w, s_out, s_b, out);
}